// Round 7
// baseline (129.767 us; speedup 1.0000x reference)
//
#include <hip/hip_runtime.h>

#define NROWS  32768
#define DIM    64
#define KCODES 1024
#define NELEM  (NROWS * DIM)   // 2097152
#define CHUNKS 8
#define CPC    (KCODES / CHUNKS)   // 128 codes per chunk-block

typedef float v2f __attribute__((ext_vector_type(2)));

// numpy-style pairwise sum of squares for n=64 contiguous fp32 (contraction
// OFF so squared temps are not fused into adds; matches jnp.sum(w*w)).
// Verified absmax 0.0 in all prior rounds. Used for se (cold path).
__device__ __forceinline__ float np_sumsq64(const float v[64]) {
#pragma clang fp contract(off)
  float r0 = v[0] * v[0];
  float r1 = v[1] * v[1];
  float r2 = v[2] * v[2];
  float r3 = v[3] * v[3];
  float r4 = v[4] * v[4];
  float r5 = v[5] * v[5];
  float r6 = v[6] * v[6];
  float r7 = v[7] * v[7];
#pragma unroll
  for (int i = 8; i < 64; i += 8) {
    r0 += v[i + 0] * v[i + 0];
    r1 += v[i + 1] * v[i + 1];
    r2 += v[i + 2] * v[i + 2];
    r3 += v[i + 3] * v[i + 3];
    r4 += v[i + 4] * v[i + 4];
    r5 += v[i + 5] * v[i + 5];
    r6 += v[i + 6] * v[i + 6];
    r7 += v[i + 7] * v[i + 7];
  }
  return ((r0 + r1) + (r2 + r3)) + ((r4 + r5) + (r6 + r7));
}

// Init (grid 128x256): keys to +inf, per-code ||e||^2 (first 1024 threads).
__global__ __launch_bounds__(256) void vq_prep(const float* __restrict__ w,
                                               float* __restrict__ se,
                                               unsigned long long* __restrict__ keys) {
  const int t = blockIdx.x * 256 + threadIdx.x;  // 0..32767
  keys[t] = ~0ull;

  if (t < KCODES) {
    float v[64];
    const float4* wr = (const float4*)(w + (size_t)t * DIM);
#pragma unroll
    for (int i = 0; i < 16; ++i) {
      float4 q = wr[i];
      v[4 * i + 0] = q.x; v[4 * i + 1] = q.y;
      v[4 * i + 2] = q.z; v[4 * i + 3] = q.w;
    }
    se[t] = np_sumsq64(v);
  }
}

// Phase 2: distances + argmin, M=1, HYBRID w-feed (8 float4 LDS broadcast +
// 8 float4 scalar path).
// Session model (rounds 1-6): issue is pinned at ~35us (2x the 17.5us clean
// floor; allocator AGPR-homes x and pays per-use moves — unfixable, three
// residency knobs tried) and the scalar-only feed adds ~45% stall (one code
// = 64 SGPRs; the ~102-SGPR file cannot double-buffer — SGPR_Count=112 every
// round). Calibrated pipes: uniform ds_read_b128 broadcast = 5.86 cyc (R3:
// 85us / 17 reads); scalar-only = 62-68us (R1/R6); LDS-only = 85us (R3).
// Hybrid at M=1: LDS = 2048 wave-codes/CU x 8 x 5.86 ~= 40us/CU ceiling;
// SMEM halves to 2 s_load_dwordx16/code (32 SGPRs -> prefetch headroom, the
// stall mechanism shrinks). Both pipes run in parallel with VALU.
// fp sequence per code is op-for-op the R4-verified split (absmax 0.0):
// a0..a3 accumulate over i=0,2,..,14 ascending (textual split at i=8 only),
// ((a0+a1)+(a2+a3)), dot=s.x+s.y, d=fma(-2,dot,fl(sx+se[c])); sx = R5/R6's
// verified v2f np-tree; strict < over ascending c; u64 (dist_bits<<32)|c
// atomicMin merges chunks (lowest-index tie-break).
// Grid 1024 = 128 row-groups (256 rows) x 8 chunks = 4 blocks/CU x 4 waves.
// LDS 16KB/block -> 64KB/CU (not limiting). XCD-bijective swizzle
// l=(bid&7)*128+(bid>>3): a group's 8 chunk-blocks share one XCD (x fetched
// from HBM once; keys atomics intra-XCD).
__global__ __launch_bounds__(256, 4) void vq_dist(const float* __restrict__ x,
                                                  const float* __restrict__ w,
                                                  const float* __restrict__ se,
                                                  unsigned long long* __restrict__ keys) {
  __shared__ float4 wlo[CPC][8];   // float4s 0..7 of each code, 16 KB
  const int bid = blockIdx.x;
  const int l = (bid & 7) * 128 + (bid >> 3);  // XCD-bijective (1024 = 8*128)
  const int group = l >> 3;                    // 0..127
  const int chunk = l & 7;                     // 0..7
  const int t = threadIdx.x;
  const int row = group * 256 + t;
  const int c0 = chunk * CPC;
  const float4* w4 = (const float4*)w;

  // Stage low halves: CPC*8 = 1024 float4s, 4 per thread (coalesced-ish;
  // one-time 16KB, L2-served for all but the first block of the chunk).
#pragma unroll
  for (int k = 0; k < 4; ++k) {
    const int e = t + 256 * k;                 // 0..1023 = code*8 + f4
    wlo[e >> 3][e & 7] = w4[(size_t)(c0 + (e >> 3)) * 16 + (e & 7)];
  }

  // Own row -> registers as v2f pairs (xv[2i],xv[2i+1] = float4 i).
  v2f xv[32];
  const float4* xr = (const float4*)(x + (size_t)row * DIM);
#pragma unroll
  for (int i = 0; i < 16; ++i) {
    float4 q = xr[i];
    xv[2 * i + 0] = (v2f){q.x, q.y};
    xv[2 * i + 1] = (v2f){q.z, q.w};
  }

  // sx via the verified np tree in v2f form (R5/R6, absmax 0.0).
  float sx;
  {
#pragma clang fp contract(off)
    v2f A0 = xv[0] * xv[0], A1 = xv[1] * xv[1];
    v2f A2 = xv[2] * xv[2], A3 = xv[3] * xv[3];
#pragma unroll
    for (int m = 1; m < 8; ++m) {
      A0 += xv[4 * m + 0] * xv[4 * m + 0];
      A1 += xv[4 * m + 1] * xv[4 * m + 1];
      A2 += xv[4 * m + 2] * xv[4 * m + 2];
      A3 += xv[4 * m + 3] * xv[4 * m + 3];
    }
    sx = ((A0.x + A0.y) + (A1.x + A1.y)) + ((A2.x + A2.y) + (A3.x + A3.y));
  }

  __syncthreads();

  float bd = __builtin_inff();
  int bc = 0;

#pragma unroll 2
  for (int j = 0; j < CPC; ++j) {
    const int c = c0 + j;
    const float4* wl = &wlo[j][0];             // uniform -> LDS broadcast
    const float4* wh = w4 + (size_t)c * 16;    // uniform -> scalar loads
    v2f a0 = (v2f){0.f, 0.f}, a1 = (v2f){0.f, 0.f};
    v2f a2 = (v2f){0.f, 0.f}, a3 = (v2f){0.f, 0.f};
#pragma unroll
    for (int i = 0; i < 8; i += 2) {           // float4s 0..7 (LDS)
      float4 t0 = wl[i];
      float4 t1 = wl[i + 1];
      a0 += (v2f){t0.x, t0.y} * xv[2 * i + 0];   // v_pk_fma_f32
      a1 += (v2f){t0.z, t0.w} * xv[2 * i + 1];
      a2 += (v2f){t1.x, t1.y} * xv[2 * i + 2];
      a3 += (v2f){t1.z, t1.w} * xv[2 * i + 3];
    }
#pragma unroll
    for (int i = 8; i < 16; i += 2) {          // float4s 8..15 (SMEM)
      float4 t0 = wh[i];
      float4 t1 = wh[i + 1];
      a0 += (v2f){t0.x, t0.y} * xv[2 * i + 0];
      a1 += (v2f){t0.z, t0.w} * xv[2 * i + 1];
      a2 += (v2f){t1.x, t1.y} * xv[2 * i + 2];
      a3 += (v2f){t1.z, t1.w} * xv[2 * i + 3];
    }
    v2f s01 = a0 + a1;
    v2f s23 = a2 + a3;
    v2f s = s01 + s23;
    float dot = s.x + s.y;
    float d = fmaf(-2.0f, dot, sx + se[c]);
    if (d < bd) { bd = d; bc = c; }
  }

  unsigned long long key =
      ((unsigned long long)__float_as_uint(bd) << 32) | (unsigned long long)(unsigned)bc;
  atomicMin(&keys[row], key);
}

// Phase 3 (grid 1024x256, 32 rows/block — R1/R6 verbatim): decode key ->
// index, indices (as float), STE output x + fl(w - x), fp64 partial ->
// part[b] plain store.
__global__ __launch_bounds__(256) void vq_out(const float* __restrict__ x,
                                              const float* __restrict__ w,
                                              const unsigned long long* __restrict__ keys,
                                              float* __restrict__ outq,
                                              float* __restrict__ outidx,
                                              double* __restrict__ part) {
  __shared__ int sidx[32];
  __shared__ double sp[4];
  const int b = blockIdx.x, t = threadIdx.x;

  if (t < 32) {
    const int row = b * 32 + t;
    unsigned long long k = keys[row];
    const int idx = (int)(unsigned int)(k & 0xFFFFFFFFull);
    outidx[row] = (float)idx;
    sidx[t] = idx;
  }
  __syncthreads();

  double acc = 0.0;
  const float4* x4 = (const float4*)x;
  float4* o4 = (float4*)outq;
#pragma unroll
  for (int i = 0; i < 2; ++i) {
    const int e = i * 256 + t;          // 0..511 float4s of this block's rows
    const int rl = e >> 4;              // local row (0..31)
    const int d4 = e & 15;              // float4 within the row
    const size_t gofs = ((size_t)b * 32 + rl) * 16 + d4;
    float4 xvv = x4[gofs];
    const float4* wr = (const float4*)(w + (size_t)sidx[rl] * DIM);
    float4 wv = wr[d4];
    float tx = wv.x - xvv.x, ty = wv.y - xvv.y;
    float tz = wv.z - xvv.z, tw = wv.w - xvv.w;
    float4 q;
    q.x = xvv.x + tx; q.y = xvv.y + ty;   // ref STE: x + fl(w - x)
    q.z = xvv.z + tz; q.w = xvv.w + tw;
    o4[gofs] = q;
    acc += (double)tx * tx + (double)ty * ty + (double)tz * tz + (double)tw * tw;
  }

#pragma unroll
  for (int s = 32; s > 0; s >>= 1) acc += __shfl_down(acc, s, 64);
  if ((t & 63) == 0) sp[t >> 6] = acc;
  __syncthreads();
  if (t == 0) part[b] = (sp[0] + sp[1]) + (sp[2] + sp[3]);
}

// Phase 4 (R1/R6 verbatim): reduce 1024 f64 partials, loss = 0.5 * mean.
__global__ __launch_bounds__(256) void vq_fin(const double* __restrict__ part,
                                              float* __restrict__ outloss) {
  __shared__ double sp[4];
  const int t = threadIdx.x;
  double a = (part[t] + part[t + 256]) + (part[t + 512] + part[t + 768]);
#pragma unroll
  for (int s = 32; s > 0; s >>= 1) a += __shfl_down(a, s, 64);
  if ((t & 63) == 0) sp[t >> 6] = a;
  __syncthreads();
  if (t == 0) {
    double total = (sp[0] + sp[1]) + (sp[2] + sp[3]);
    *outloss = 0.5f * (float)(total / (double)NELEM);
  }
}

extern "C" void kernel_launch(void* const* d_in, const int* in_sizes, int n_in,
                              void* d_out, int out_size, void* d_ws, size_t ws_size,
                              hipStream_t stream) {
  const float* x = (const float*)d_in[0];   // inputs (32,64,32,32) fp32
  const float* w = (const float*)d_in[1];   // weight (1024,64) fp32

  float* outq    = (float*)d_out;           // [0, 2097152)
  float* outidx  = outq + NELEM;            // [2097152, +32768)
  float* outloss = outidx + NROWS;          // [2129920]

  char* wsb = (char*)d_ws;
  float* se    = (float*)(wsb + 256);                               // 4 KB
  double* part = (double*)(wsb + 8192);                             // 8 KB
  unsigned long long* keys = (unsigned long long*)(wsb + 147456);   // 256 KB

  hipLaunchKernelGGL(vq_prep, dim3(128),  dim3(256), 0, stream, w, se, keys);
  hipLaunchKernelGGL(vq_dist, dim3(1024), dim3(256), 0, stream, x, w, se, keys);
  hipLaunchKernelGGL(vq_out,  dim3(1024), dim3(256), 0, stream, x, w, keys, outq, outidx, part);
  hipLaunchKernelGGL(vq_fin,  dim3(1),    dim3(256), 0, stream, part, outloss);
}